// Round 18
// baseline (787.678 us; speedup 1.0000x reference)
//
#include <hip/hip_runtime.h>
#include <hip/hip_bf16.h>
#include <hip/hip_fp8.h>

typedef unsigned short u16;
typedef unsigned int u32;
typedef unsigned char u8;
typedef __attribute__((ext_vector_type(4))) float fx4;
typedef __attribute__((ext_vector_type(8))) __bf16 bf8;

#define NEGV -1e9f
#define LOG2E 1.4426950408889634f
#define SCALE2 (0.17677669529663687f*1.4426950408889634f)

static __device__ __forceinline__ u16 f2bu(float f){
    __hip_bfloat16 h = __float2bfloat16(f);
    return *reinterpret_cast<u16*>(&h);
}
static __device__ __forceinline__ float b2f(u16 u){
    __hip_bfloat16 h;
    *reinterpret_cast<u16*>(&h) = u;
    return __bfloat162float(h);
}
static __device__ __forceinline__ u8 f2f8(float v){
    __hip_fp8_e4m3 t(v);
    return *reinterpret_cast<u8*>(&t);
}
static __device__ __forceinline__ float frcp(float x){
#if __has_builtin(__builtin_amdgcn_rcpf)
    return __builtin_amdgcn_rcpf(x);
#else
    return 1.f/x;
#endif
}
static __device__ __forceinline__ float frsq(float x){
#if __has_builtin(__builtin_amdgcn_rsqf)
    return __builtin_amdgcn_rsqf(x);
#else
    return rsqrtf(x);
#endif
}
// GELU via v*sigmoid(1.702v) — error below the fp8 h-buffer quantization noise.
static __device__ __forceinline__ float gelu_f(float v){
    return v * frcp(1.f + __builtin_amdgcn_exp2f(-2.4554418f*v));
}

// ---- K0a: Wo -> bf16 ; W2*16 -> fp8 e4m3 ----
__global__ __launch_bounds__(256) void f2b2_kernel(
        const float* __restrict__ s1, const float* __restrict__ s3,
        u16* __restrict__ d1, u8* __restrict__ d3){
    int i = blockIdx.x*256 + threadIdx.x;
    if (i < 36864)  d1[i] = f2bu(s1[i]);
    if (i < 147456) d3[i] = f2f8(s3[i]*16.f);
}

// ---- K0b: LN-folded weights ----
__global__ __launch_bounds__(256) void wprep_kernel(
        const float* __restrict__ qkv_w, const float* __restrict__ g1, const float* __restrict__ b1,
        const float* __restrict__ w1,    const float* __restrict__ g2, const float* __restrict__ b2,
        const float* __restrict__ mb1,
        u16* __restrict__ WqP, float* __restrict__ wsq, float* __restrict__ ccq,
        u16* __restrict__ W1P, float* __restrict__ ws1, float* __restrict__ cc1){
    const int row = blockIdx.x*4 + (threadIdx.x>>6);
    const int l = threadIdx.x & 63;
    const int isq = row < 576;
    const int n = isq ? row : row - 576;
    if (row >= 1344) return;
    const float* src = (isq ? qkv_w : w1) + (size_t)n*192;
    const float* g = isq ? g1 : g2;
    const float* b = isq ? b1 : b2;
    u16* dst = (isq ? WqP : W1P) + (size_t)n*192;
    float sw = 0.f, sc = 0.f;
    #pragma unroll
    for (int t=0;t<3;t++){
        const int k = l + t*64;
        const float wv = src[k];
        const float wp = wv*g[k];
        dst[k] = f2bu(wp);
        sw += wp; sc += b[k]*wv;
    }
    #pragma unroll
    for (int o=32;o;o>>=1){ sw += __shfl_xor(sw,o,64); sc += __shfl_xor(sc,o,64); }
    if (!l){
        if (isq){ wsq[n]=sw; ccq[n]=sc; }
        else    { ws1[n]=sw; cc1[n]=sc + mb1[n]; }
    }
}

// ---- fused logit table, PER-LANE FRAGMENT LAYOUT:
// LT[cls*6+h][lane][ti][reg][tj] = (rel_bias + shift_mask)*LOG2E, NEG pads.
__global__ __launch_bounds__(256) void ltab_kernel(const float* __restrict__ rel_table,
                                                   float* __restrict__ LT){
    const int blk = blockIdx.x;           // cls*6 + h
    const int cls = blk/6, h = blk - cls*6;
    float* T = LT + blk*4096;
    for (int e = threadIdx.x; e < 4096; e += 256){
        const int lane = e>>6, rem = e&63;
        const int ti = rem>>4, reg = (rem>>2)&3, tj = rem&3;
        const int lg = lane>>4, lr = lane&15;
        const int i = ti*16 + lg*4 + reg;
        const int j = tj*16 + lr;
        float v = NEGV;
        if (i < 49 && j < 49){
            const int id = i/7, im = i-id*7, jd = j/7, jm = j-jd*7;
            const int ridx = (id-jd+6)*13 + (im-jm+6);
            const float bias = rel_table[ridx*6 + h];
            const int ri = (cls&2) ? (id<4?1:2) : 0;
            const int rj = (cls&2) ? (jd<4?1:2) : 0;
            const int ci = (cls&1) ? (im<4?1:2) : 0;
            const int cj = (cls&1) ? (jm<4?1:2) : 0;
            v = bias + ((ri==rj && ci==cj) ? 0.f : NEGV);
        }
        T[e] = v * LOG2E;
    }
}

// ---- K1: roll(-3,-3) + window partition; LN1 stats only ----
__global__ __launch_bounds__(256) void partition_ln_kernel(
        const float* __restrict__ x, u16* __restrict__ xw, float2* __restrict__ RS1){
    __shared__ float lds[192*57];
    const int bi = blockIdx.x;
    const int b = bi/56, i = bi%56;
    const int si = (i+3)%56;
    const float* src = x + (size_t)b*602112 + (size_t)si*56;
    for (int e = threadIdx.x; e < 10752; e += 256){
        int c = e/56, j = e%56;
        lds[c*57 + j] = src[(size_t)c*3136 + j];
    }
    __syncthreads();
    const int wrow_base = (b*8 + i/7)*8;
    const int prow = (i%7)*7;
    for (int e = threadIdx.x; e < 10752; e += 256){
        int j = e/192, c = e%192;
        int t = (wrow_base + j/7)*49 + prow + (j%7);
        xw[(size_t)t*192 + c] = f2bu(lds[c*57 + (j+3)%56]);
    }
    const int wv = threadIdx.x>>6, l = threadIdx.x&63;
    for (int j = wv; j < 56; j += 4){
        const int jj = (j+3)%56;
        float v0 = lds[l*57 + jj], v1 = lds[(l+64)*57 + jj], v2 = lds[(l+128)*57 + jj];
        float s = v0+v1+v2;
        #pragma unroll
        for (int o=32;o;o>>=1) s += __shfl_xor(s, o, 64);
        const float mean = s*(1.f/192.f);
        float d0 = v0-mean, d1 = v1-mean, d2 = v2-mean;
        float qv = d0*d0 + d1*d1 + d2*d2;
        #pragma unroll
        for (int o=32;o;o>>=1) qv += __shfl_xor(qv, o, 64);
        const float rstd = frsq(qv*(1.f/192.f) + 1e-5f);
        if (l == 0){
            const int t = (wrow_base + j/7)*49 + prow + (j%7);
            RS1[t] = make_float2(mean, rstd);
        }
    }
}

// ---- K9: window reverse + roll(+3,+3): bf16 -> f32 ----
__global__ __launch_bounds__(256) void reverse_kernel(const u16* __restrict__ xw, float* __restrict__ out){
    __shared__ float lds[192*57];
    const int bi = blockIdx.x;
    const int b = bi/56, h = bi%56;
    const int i = (h+53)%56;
    const int wrow_base = (b*8 + i/7)*8;
    const int prow = (i%7)*7;
    for (int e = threadIdx.x; e < 10752; e += 256){
        int j = e/192, c = e%192;
        int t = (wrow_base + j/7)*49 + prow + (j%7);
        lds[c*57 + j] = b2f(xw[(size_t)t*192 + c]);
    }
    __syncthreads();
    float* dst = out + (size_t)b*602112 + (size_t)h*56;
    for (int e = threadIdx.x; e < 10752; e += 256){
        int c = e/56, w = e%56;
        dst[(size_t)c*3136 + w] = lds[c*57 + (w+53)%56];
    }
}

// ---- staging: global -> LDS, 128-byte-wide tile rows, XOR-pre-swizzled source ----
template<int ROWS>
static __device__ __forceinline__ void stage_tile(const char* __restrict__ g, size_t row0,
                                                  int kc, int pitch, u16* ldsbase, int tid){
    const int w = tid>>6, lane = tid&63;
    const int sub = lane>>3;
    const int b16 = (lane&7) ^ sub;
    #pragma unroll
    for (int i=0; i<ROWS/32; ++i){
        const int row = i*32 + w*8 + sub;
        const char* src = g + (row0+row)*(size_t)pitch + (size_t)kc*128 + b16*16;
        u16* dst = ldsbase + i*2048 + w*512;
#if __has_builtin(__builtin_amdgcn_global_load_lds)
        __builtin_amdgcn_global_load_lds(
            (const __attribute__((address_space(1))) u32*)src,
            (__attribute__((address_space(3))) u32*)dst, 16, 0, 0);
#else
        *(uint4*)(dst + lane*8) = *(const uint4*)src;
#endif
    }
}

static __device__ __forceinline__ bf8 rd_frag16(const u16* lds, int row, int boff){
    const char* p = (const char*)lds + row*128 + (boff ^ ((row&7)<<4));
    return *(const bf8*)p;
}
static __device__ __forceinline__ long rd_frag8(const u16* lds, int row, int boff){
    const char* p = (const char*)lds + row*128 + (boff ^ ((row&7)<<4));
    return *(const long*)p;
}

// ---- pipelined GEMM: BM=128, BN=192, 128B K-chunks, double-buffered ----
template<int KEL,int ESZ,int NY,int NTOT,int ACT,int RES,int LNF,int STATS,int OUT,int HASB>
__global__ __launch_bounds__(256,2) void gemm_kernel(
    const void* __restrict__ Av, const void* __restrict__ Bv,
    const float* __restrict__ bias, const u16* __restrict__ res,
    void* __restrict__ out,
    const float2* __restrict__ RSin, const float* __restrict__ wsum,
    const float* __restrict__ cc, float2* __restrict__ RSout,
    float ascale)
{
    constexpr int NKT = (KEL*ESZ)/128;
    constexpr int KKS = (ESZ==1)?4:2;
    constexpr int PITCH = KEL*ESZ;
    __shared__ __align__(16) u16 lds[40960];
    const int tid = threadIdx.x;
    const int wv = tid>>6, l = tid&63, lr = l&15, lg = l>>4;
    const int wm = wv&1, wn = wv>>1;
    const int chunk = gridDim.x >> 3;
    const int orig = (blockIdx.x & 7)*chunk + (blockIdx.x >> 3);
    const int mt = orig / NY;
    const int nc = orig - mt*NY;
    const size_t row0 = (size_t)mt*128;
    const int n0 = nc*192;
    const char* A = (const char*)Av;
    const char* Bblk = (const char*)Bv + (size_t)n0*PITCH;

    stage_tile<128>(A, row0, 0, PITCH, lds, tid);
    stage_tile<192>(Bblk, 0, 0, PITCH, lds+16384, tid);
    __syncthreads();

    fx4 acc[4][6] = {};
    for (int kc=0; kc<NKT; ++kc){
        const int cur = kc & 1;
        u16* Ac = cur ? (u16*)lds+8192  : (u16*)lds;
        u16* Bc = cur ? (u16*)lds+28672 : (u16*)lds+16384;
        if (kc+1 < NKT){
            u16* An = cur ? (u16*)lds       : (u16*)lds+8192;
            u16* Bn = cur ? (u16*)lds+16384 : (u16*)lds+28672;
            stage_tile<128>(A, row0, kc+1, PITCH, An, tid);
            stage_tile<192>(Bblk, 0, kc+1, PITCH, Bn, tid);
        }
        #pragma unroll
        for (int kk=0; kk<KKS; ++kk){
            if constexpr (ESZ==2){
                bf8 af[4], bfr[6];
                #pragma unroll
                for (int r=0;r<4;r++) af[r]  = rd_frag16(Ac, wm*64 + r*16 + lr, kk*64 + lg*16);
                #pragma unroll
                for (int c=0;c<6;c++) bfr[c] = rd_frag16(Bc, wn*96 + c*16 + lr, kk*64 + lg*16);
                #pragma unroll
                for (int r=0;r<4;r++)
                    #pragma unroll
                    for (int c=0;c<6;c++)
                        acc[r][c] = __builtin_amdgcn_mfma_f32_16x16x32_bf16(af[r], bfr[c], acc[r][c], 0,0,0);
            } else {
                long af[4], bfr[6];
                #pragma unroll
                for (int r=0;r<4;r++) af[r]  = rd_frag8(Ac, wm*64 + r*16 + lr, kk*32 + lg*8);
                #pragma unroll
                for (int c=0;c<6;c++) bfr[c] = rd_frag8(Bc, wn*96 + c*16 + lr, kk*32 + lg*8);
                #pragma unroll
                for (int r=0;r<4;r++)
                    #pragma unroll
                    for (int c=0;c<6;c++)
                        acc[r][c] = __builtin_amdgcn_mfma_f32_16x16x32_fp8_fp8(af[r], bfr[c], acc[r][c], 0,0,0);
            }
        }
        __syncthreads();
    }

    // ---- epilogue ----
    float sA[4][4], sB[4][4];
    if constexpr (LNF){
        #pragma unroll
        for (int r=0;r<4;r++)
            #pragma unroll
            for (int q=0;q<4;q++){
                const float2 st = RSin[row0 + wm*64 + r*16 + lg*4 + q];
                sA[r][q] = st.y;
                sB[r][q] = -st.x*st.y;
            }
    }
    float ss[4][4], ss2[4][4];
    if constexpr (STATS){
        #pragma unroll
        for (int r=0;r<4;r++)
            #pragma unroll
            for (int q=0;q<4;q++){ ss[r][q]=0.f; ss2[r][q]=0.f; }
    }
    #pragma unroll
    for (int c=0;c<6;c++){
        const int col = n0 + wn*96 + c*16 + lr;
        float bv = 0.f, wsc = 0.f, ccc = 0.f;
        if constexpr (HASB) bv = bias[col];
        if constexpr (LNF){ wsc = wsum[col]; ccc = cc[col]; }
        #pragma unroll
        for (int r=0;r<4;r++){
            const size_t grow0 = row0 + wm*64 + r*16 + lg*4;
            float vq[4];
            #pragma unroll
            for (int q=0;q<4;q++){
                float v = acc[r][c][q];
                if constexpr (ESZ==1) v *= ascale;
                if constexpr (LNF) v = fmaf(v, sA[r][q], fmaf(sB[r][q], wsc, ccc));
                else v += bv;
                if constexpr (ACT) v = gelu_f(v);
                if constexpr (RES) v += b2f(res[(grow0+q)*NTOT + col]);
                if constexpr (STATS){ ss[r][q] += v; ss2[r][q] += v*v; }
                vq[q] = v;
            }
            if constexpr (OUT==1){
                u16* ob = (u16*)out + grow0*NTOT + col;
                ob[0] = f2bu(vq[0]);
                ob[NTOT] = f2bu(vq[1]);
                ob[2*NTOT] = f2bu(vq[2]);
                ob[3*NTOT] = f2bu(vq[3]);
            } else {
                u8* ob = (u8*)out + grow0*(size_t)NTOT + col;
#if __has_builtin(__builtin_amdgcn_cvt_pk_fp8_f32)
                const u32 p01 = (u32)__builtin_amdgcn_cvt_pk_fp8_f32(vq[0], vq[1], 0, false);
                const u32 p23 = (u32)__builtin_amdgcn_cvt_pk_fp8_f32(vq[2], vq[3], 0, false);
                ob[0] = (u8)p01;
                ob[NTOT] = (u8)(p01>>8);
                ob[2*NTOT] = (u8)p23;
                ob[3*NTOT] = (u8)(p23>>8);
#else
                ob[0] = f2f8(vq[0]);
                ob[NTOT] = f2f8(vq[1]);
                ob[2*NTOT] = f2f8(vq[2]);
                ob[3*NTOT] = f2f8(vq[3]);
#endif
            }
        }
    }
    if constexpr (STATS){
        float* redS = (float*)lds;     // [2][128][2]
        #pragma unroll
        for (int r=0;r<4;r++)
            #pragma unroll
            for (int q=0;q<4;q++){
                float s = ss[r][q], s2 = ss2[r][q];
                #pragma unroll
                for (int o=8;o;o>>=1){ s += __shfl_xor(s, o, 64); s2 += __shfl_xor(s2, o, 64); }
                if (lr == 0){
                    const int rowl = wm*64 + r*16 + lg*4 + q;
                    redS[(wn*128 + rowl)*2 + 0] = s;
                    redS[(wn*128 + rowl)*2 + 1] = s2;
                }
            }
        __syncthreads();
        for (int row = tid; row < 128; row += 256){
            const float S  = redS[row*2+0] + redS[(128+row)*2+0];
            const float S2 = redS[row*2+1] + redS[(128+row)*2+1];
            const float mean = S*(1.f/192.f);
            const float rstd = frsq(S2*(1.f/192.f) - mean*mean + 1e-5f);
            RSout[row0 + row] = make_float2(mean, rstd);
        }
    }
}

// ---- attention: 2 waves/block, grid-stride over (window, head-pair) items ----
__global__ __launch_bounds__(128) void attn_kernel(const u16* __restrict__ qkv,
                                                   const float* __restrict__ LT,
                                                   u16* __restrict__ o)
{
    __shared__ u16 paS[2][50*64];
    __shared__ u16 vtS[2][32*64];
    const int w2 = threadIdx.x>>6;
    u16* pa = paS[w2];
    u16* vt = vtS[w2];
    const int l = threadIdx.x & 63, lr = l&15, lg = l>>4;

    for (int item = blockIdx.x; item < 12288; item += gridDim.x){
        const int widx = item/3, hp = item - widx*3;
        const int h = hp*2 + w2;
        const int wi = widx & 63;
        const int nhi = wi>>3, nwi = wi&7;
        const u16* base = qkv + (size_t)widx*49*576;
        const int cls = ((nhi==7)?2:0) | ((nwi==7)?1:0);
        const float* Ths = LT + (size_t)(cls*6 + h)*4096 + l*64;

        bf8 qf[4], kf[4];
        #pragma unroll
        for (int t=0;t<4;t++){
            const int row = min(t*16 + lr, 48);
            qf[t] = *(const bf8*)(base + (size_t)row*576 + h*32 + lg*8);
            kf[t] = *(const bf8*)(base + (size_t)row*576 + 192 + h*32 + lg*8);
        }
        for (int e=l; e<480; e+=64){
            int d = e/15, j = 49 + (e - d*15);
            vt[d*64 + (j ^ (((d>>1)&7)<<3))] = 0;
        }
        for (int e=l; e<784; e+=64){
            int j = e>>4, dp = e&15;
            u32 val = *(const u32*)(base + (size_t)j*576 + 384 + h*32 + dp*2);
            const int d0 = dp*2, d1 = d0+1;
            vt[d0*64 + (j ^ ((dp&7)<<3))] = (u16)(val & 0xffffu);
            vt[d1*64 + (j ^ ((dp&7)<<3))] = (u16)(val >> 16);
        }

        fx4 acc[4][4] = {};
        #pragma unroll
        for (int ti=0;ti<4;ti++)
            #pragma unroll
            for (int tj=0;tj<4;tj++)
                acc[ti][tj] = __builtin_amdgcn_mfma_f32_16x16x32_bf16(qf[ti], kf[tj], acc[ti][tj], 0,0,0);

        #pragma unroll
        for (int ti=0;ti<4;ti++){
            #pragma unroll
            for (int reg=0;reg<4;reg++){
                const fx4 lt = *(const fx4*)(Ths + ti*16 + reg*4);
                #pragma unroll
                for (int tj=0;tj<4;tj++)
                    acc[ti][tj][reg] = fmaf(acc[ti][tj][reg], SCALE2, lt[tj]);
            }
        }
        float sums[4][4];
        #pragma unroll
        for (int ti=0;ti<4;ti++){
            #pragma unroll
            for (int reg=0;reg<4;reg++){
                float mx = fmaxf(fmaxf(acc[ti][0][reg], acc[ti][1][reg]),
                                 fmaxf(acc[ti][2][reg], acc[ti][3][reg]));
                #pragma unroll
                for (int o2=8;o2;o2>>=1) mx = fmaxf(mx, __shfl_xor(mx, o2, 64));
                float sum = 0.f;
                #pragma unroll
                for (int tj=0;tj<4;tj++){
                    float p = __builtin_amdgcn_exp2f(acc[ti][tj][reg] - mx);
                    acc[ti][tj][reg] = p;
                    sum += p;
                }
                #pragma unroll
                for (int o2=8;o2;o2>>=1) sum += __shfl_xor(sum, o2, 64);
                sums[ti][reg] = sum;
            }
        }
        #pragma unroll
        for (int ti=0;ti<4;ti++)
            #pragma unroll
            for (int tj=0;tj<4;tj++)
                #pragma unroll
                for (int reg=0;reg<4;reg++){
                    const int row = ti*16 + lg*4 + reg;
                    if (row < 50)
                        pa[row*64 + ((tj*16+lr) ^ ((row&7)<<3))] = f2bu(acc[ti][tj][reg]);
                }
        __syncthreads();

        fx4 oacc[4][2] = {};
        #pragma unroll
        for (int kk=0;kk<2;kk++){
            bf8 bfr[2];
            #pragma unroll
            for (int cd=0;cd<2;cd++){
                const int rowb = cd*16 + lr;
                bfr[cd] = *(const bf8*)(vt + rowb*64 + ((kk*32 + lg*8) ^ (((rowb>>1)&7)<<3)));
            }
            #pragma unroll
            for (int ti=0;ti<4;ti++){
                const int rowa = min(ti*16 + lr, 49);
                bf8 afr = *(const bf8*)(pa + rowa*64 + ((kk*32 + lg*8) ^ ((rowa&7)<<3)));
                #pragma unroll
                for (int cd=0;cd<2;cd++)
                    oacc[ti][cd] = __builtin_amdgcn_mfma_f32_16x16x32_bf16(afr, bfr[cd], oacc[ti][cd], 0,0,0);
            }
        }
        u16* ob = o + (size_t)widx*49*192 + h*32;
        #pragma unroll
        for (int ti=0;ti<4;ti++){
            float rsv[4];
            #pragma unroll
            for (int q=0;q<4;q++) rsv[q] = frcp(sums[ti][q]);
            #pragma unroll
            for (int cd=0;cd<2;cd++)
                #pragma unroll
                for (int q=0;q<4;q++){
                    const int i = ti*16 + lg*4 + q;
                    if (i < 49) ob[(size_t)i*192 + cd*16 + lr] = f2bu(oacc[ti][cd][q]*rsv[q]);
                }
        }
        __syncthreads();
    }
}

extern "C" void kernel_launch(void* const* d_in, const int* in_sizes, int n_in,
                              void* d_out, int out_size, void* d_ws, size_t ws_size,
                              hipStream_t stream)
{
    const float* x      = (const float*)d_in[0];
    const float* ln1_g  = (const float*)d_in[1];
    const float* ln1_b  = (const float*)d_in[2];
    const float* qkv_w  = (const float*)d_in[3];
    const float* out_w  = (const float*)d_in[4];
    const float* out_b  = (const float*)d_in[5];
    const float* ln2_g  = (const float*)d_in[6];
    const float* ln2_b  = (const float*)d_in[7];
    const float* mlp_w1 = (const float*)d_in[8];
    const float* mlp_b1 = (const float*)d_in[9];
    const float* mlp_w2 = (const float*)d_in[10];
    const float* mlp_b2 = (const float*)d_in[11];
    const float* rel_t  = (const float*)d_in[12];

    char* ws = (char*)d_ws;
    u16*    Ybuf  = (u16*)ws;                    // O (attn out) / xw3 bf16 [T,192]
    float*  LTab  = (float*)(ws + 77070336);
    float2* RS1   = (float2*)(ws + 77600000);
    float2* RS2   = (float2*)(ws + 79300000);
    u16*    WqP   = (u16*)(ws + 81000000);
    float*  wsq   = (float*)(ws + 81300000);
    float*  ccq   = (float*)(ws + 81310000);
    u16*    W1P   = (u16*)(ws + 81400000);
    float*  ws1   = (float*)(ws + 81700000);
    float*  cc1   = (float*)(ws + 81710000);
    u16*    XWbuf = (u16*)(ws + 154140672);
    u16*    QKVH  = (u16*)(ws + 231211008);
    u8*     Hbuf  = (u8*)(ws + 231211008);
    u16*    Wo    = (u16*)(ws + 539492352);
    u8*     W2f8  = (u8*)(ws + 539492352 + 73728);

    f2b2_kernel<<<576,256,0,stream>>>(out_w, mlp_w2, Wo, W2f8);
    wprep_kernel<<<336,256,0,stream>>>(qkv_w, ln1_g, ln1_b, mlp_w1, ln2_g, ln2_b, mlp_b1,
                                       WqP, wsq, ccq, W1P, ws1, cc1);
    ltab_kernel<<<24,256,0,stream>>>(rel_t, LTab);

    // partition + LN1 stats
    partition_ln_kernel<<<3584,256,0,stream>>>(x, XWbuf, RS1);
    // qkv = LN1(xw) @ Wq^T (folded) : [T,576] bf16
    gemm_kernel<192,2,3,576,0,0,1,0,1,0><<<4704,256,0,stream>>>(
        XWbuf, WqP, nullptr, nullptr, QKVH, RS1, wsq, ccq, nullptr, 1.f);
    attn_kernel<<<2048,128,0,stream>>>(QKVH, LTab, Ybuf);
    // xw2 = xw + O @ Wo^T + b (bf16, in-place); LN2 stats -> RS2
    gemm_kernel<192,2,1,192,0,1,0,1,1,1><<<1568,256,0,stream>>>(
        Ybuf, Wo, out_b, XWbuf, XWbuf, nullptr, nullptr, nullptr, RS2, 1.f);
    // h = gelu(LN2(xw2) @ W1^T + b1) (folded) : [T,768] fp8
    gemm_kernel<192,2,4,768,1,0,1,0,2,0><<<6272,256,0,stream>>>(
        XWbuf, W1P, nullptr, nullptr, Hbuf, RS2, ws1, cc1, nullptr, 1.f);
    // xw3 = xw2 + (h @ W2f8^T)/16 + b2 : bf16 -> Ybuf
    gemm_kernel<768,1,1,192,0,1,0,0,1,1><<<1568,256,0,stream>>>(
        Hbuf, W2f8, mlp_b2, XWbuf, Ybuf, nullptr, nullptr, nullptr, nullptr, 0.0625f);
    reverse_kernel<<<3584,256,0,stream>>>(Ybuf, (float*)d_out);
}

// Round 19
// 680.417 us; speedup vs baseline: 1.1576x; 1.1576x over previous
//
#include <hip/hip_runtime.h>
#include <hip/hip_bf16.h>
#include <hip/hip_fp8.h>

typedef unsigned short u16;
typedef unsigned int u32;
typedef unsigned char u8;
typedef __attribute__((ext_vector_type(4))) float fx4;
typedef __attribute__((ext_vector_type(8))) __bf16 bf8;

#define NEGV -1e9f
#define LOG2E 1.4426950408889634f
#define SCALE2 (0.17677669529663687f*1.4426950408889634f)

static __device__ __forceinline__ u16 f2bu(float f){
    __hip_bfloat16 h = __float2bfloat16(f);
    return *reinterpret_cast<u16*>(&h);
}
static __device__ __forceinline__ float b2f(u16 u){
    __hip_bfloat16 h;
    *reinterpret_cast<u16*>(&h) = u;
    return __bfloat162float(h);
}
static __device__ __forceinline__ u8 f2f8(float v){
    __hip_fp8_e4m3 t(v);
    return *reinterpret_cast<u8*>(&t);
}
static __device__ __forceinline__ float frcp(float x){
#if __has_builtin(__builtin_amdgcn_rcpf)
    return __builtin_amdgcn_rcpf(x);
#else
    return 1.f/x;
#endif
}
static __device__ __forceinline__ float frsq(float x){
#if __has_builtin(__builtin_amdgcn_rsqf)
    return __builtin_amdgcn_rsqf(x);
#else
    return rsqrtf(x);
#endif
}
// GELU via v*sigmoid(1.702v) — error below the fp8 h-buffer quantization noise.
static __device__ __forceinline__ float gelu_f(float v){
    return v * frcp(1.f + __builtin_amdgcn_exp2f(-2.4554418f*v));
}

// ---- K0a: Wo -> bf16 ; W2*16 -> fp8 e4m3 ----
__global__ __launch_bounds__(256) void f2b2_kernel(
        const float* __restrict__ s1, const float* __restrict__ s3,
        u16* __restrict__ d1, u8* __restrict__ d3){
    int i = blockIdx.x*256 + threadIdx.x;
    if (i < 36864)  d1[i] = f2bu(s1[i]);
    if (i < 147456) d3[i] = f2f8(s3[i]*16.f);
}

// ---- K0b: LN-folded weights ----
__global__ __launch_bounds__(256) void wprep_kernel(
        const float* __restrict__ qkv_w, const float* __restrict__ g1, const float* __restrict__ b1,
        const float* __restrict__ w1,    const float* __restrict__ g2, const float* __restrict__ b2,
        const float* __restrict__ mb1,
        u16* __restrict__ WqP, float* __restrict__ wsq, float* __restrict__ ccq,
        u16* __restrict__ W1P, float* __restrict__ ws1, float* __restrict__ cc1){
    const int row = blockIdx.x*4 + (threadIdx.x>>6);
    const int l = threadIdx.x & 63;
    const int isq = row < 576;
    const int n = isq ? row : row - 576;
    if (row >= 1344) return;
    const float* src = (isq ? qkv_w : w1) + (size_t)n*192;
    const float* g = isq ? g1 : g2;
    const float* b = isq ? b1 : b2;
    u16* dst = (isq ? WqP : W1P) + (size_t)n*192;
    float sw = 0.f, sc = 0.f;
    #pragma unroll
    for (int t=0;t<3;t++){
        const int k = l + t*64;
        const float wv = src[k];
        const float wp = wv*g[k];
        dst[k] = f2bu(wp);
        sw += wp; sc += b[k]*wv;
    }
    #pragma unroll
    for (int o=32;o;o>>=1){ sw += __shfl_xor(sw,o,64); sc += __shfl_xor(sc,o,64); }
    if (!l){
        if (isq){ wsq[n]=sw; ccq[n]=sc; }
        else    { ws1[n]=sw; cc1[n]=sc + mb1[n]; }
    }
}

// ---- fused logit table, PER-LANE FRAGMENT LAYOUT:
// LT[cls*6+h][lane][ti][reg][tj] = (rel_bias + shift_mask)*LOG2E, NEG pads.
__global__ __launch_bounds__(256) void ltab_kernel(const float* __restrict__ rel_table,
                                                   float* __restrict__ LT){
    const int blk = blockIdx.x;           // cls*6 + h
    const int cls = blk/6, h = blk - cls*6;
    float* T = LT + blk*4096;
    for (int e = threadIdx.x; e < 4096; e += 256){
        const int lane = e>>6, rem = e&63;
        const int ti = rem>>4, reg = (rem>>2)&3, tj = rem&3;
        const int lg = lane>>4, lr = lane&15;
        const int i = ti*16 + lg*4 + reg;
        const int j = tj*16 + lr;
        float v = NEGV;
        if (i < 49 && j < 49){
            const int id = i/7, im = i-id*7, jd = j/7, jm = j-jd*7;
            const int ridx = (id-jd+6)*13 + (im-jm+6);
            const float bias = rel_table[ridx*6 + h];
            const int ri = (cls&2) ? (id<4?1:2) : 0;
            const int rj = (cls&2) ? (jd<4?1:2) : 0;
            const int ci = (cls&1) ? (im<4?1:2) : 0;
            const int cj = (cls&1) ? (jm<4?1:2) : 0;
            v = bias + ((ri==rj && ci==cj) ? 0.f : NEGV);
        }
        T[e] = v * LOG2E;
    }
}

// ---- K1: roll(-3,-3) + window partition; LN1 stats only ----
__global__ __launch_bounds__(256) void partition_ln_kernel(
        const float* __restrict__ x, u16* __restrict__ xw, float2* __restrict__ RS1){
    __shared__ float lds[192*57];
    const int bi = blockIdx.x;
    const int b = bi/56, i = bi%56;
    const int si = (i+3)%56;
    const float* src = x + (size_t)b*602112 + (size_t)si*56;
    for (int e = threadIdx.x; e < 10752; e += 256){
        int c = e/56, j = e%56;
        lds[c*57 + j] = src[(size_t)c*3136 + j];
    }
    __syncthreads();
    const int wrow_base = (b*8 + i/7)*8;
    const int prow = (i%7)*7;
    for (int e = threadIdx.x; e < 10752; e += 256){
        int j = e/192, c = e%192;
        int t = (wrow_base + j/7)*49 + prow + (j%7);
        xw[(size_t)t*192 + c] = f2bu(lds[c*57 + (j+3)%56]);
    }
    const int wv = threadIdx.x>>6, l = threadIdx.x&63;
    for (int j = wv; j < 56; j += 4){
        const int jj = (j+3)%56;
        float v0 = lds[l*57 + jj], v1 = lds[(l+64)*57 + jj], v2 = lds[(l+128)*57 + jj];
        float s = v0+v1+v2;
        #pragma unroll
        for (int o=32;o;o>>=1) s += __shfl_xor(s, o, 64);
        const float mean = s*(1.f/192.f);
        float d0 = v0-mean, d1 = v1-mean, d2 = v2-mean;
        float qv = d0*d0 + d1*d1 + d2*d2;
        #pragma unroll
        for (int o=32;o;o>>=1) qv += __shfl_xor(qv, o, 64);
        const float rstd = frsq(qv*(1.f/192.f) + 1e-5f);
        if (l == 0){
            const int t = (wrow_base + j/7)*49 + prow + (j%7);
            RS1[t] = make_float2(mean, rstd);
        }
    }
}

// ---- K9: window reverse + roll(+3,+3): bf16 -> f32 ----
__global__ __launch_bounds__(256) void reverse_kernel(const u16* __restrict__ xw, float* __restrict__ out){
    __shared__ float lds[192*57];
    const int bi = blockIdx.x;
    const int b = bi/56, h = bi%56;
    const int i = (h+53)%56;
    const int wrow_base = (b*8 + i/7)*8;
    const int prow = (i%7)*7;
    for (int e = threadIdx.x; e < 10752; e += 256){
        int j = e/192, c = e%192;
        int t = (wrow_base + j/7)*49 + prow + (j%7);
        lds[c*57 + j] = b2f(xw[(size_t)t*192 + c]);
    }
    __syncthreads();
    float* dst = out + (size_t)b*602112 + (size_t)h*56;
    for (int e = threadIdx.x; e < 10752; e += 256){
        int c = e/56, w = e%56;
        dst[(size_t)c*3136 + w] = lds[c*57 + (w+53)%56];
    }
}

// ---- staging: global -> LDS, 128-byte-wide tile rows, XOR-pre-swizzled source ----
template<int ROWS>
static __device__ __forceinline__ void stage_tile(const char* __restrict__ g, size_t row0,
                                                  int kc, int pitch, u16* ldsbase, int tid){
    const int w = tid>>6, lane = tid&63;
    const int sub = lane>>3;
    const int b16 = (lane&7) ^ sub;
    #pragma unroll
    for (int i=0; i<ROWS/32; ++i){
        const int row = i*32 + w*8 + sub;
        const char* src = g + (row0+row)*(size_t)pitch + (size_t)kc*128 + b16*16;
        u16* dst = ldsbase + i*2048 + w*512;
#if __has_builtin(__builtin_amdgcn_global_load_lds)
        __builtin_amdgcn_global_load_lds(
            (const __attribute__((address_space(1))) u32*)src,
            (__attribute__((address_space(3))) u32*)dst, 16, 0, 0);
#else
        *(uint4*)(dst + lane*8) = *(const uint4*)src;
#endif
    }
}

static __device__ __forceinline__ bf8 rd_frag16(const u16* lds, int row, int boff){
    const char* p = (const char*)lds + row*128 + (boff ^ ((row&7)<<4));
    return *(const bf8*)p;
}
static __device__ __forceinline__ long rd_frag8(const u16* lds, int row, int boff){
    const char* p = (const char*)lds + row*128 + (boff ^ ((row&7)<<4));
    return *(const long*)p;
}

// ---- pipelined GEMM: BM=128, BN=192, 128B K-chunks, double-buffered ----
template<int KEL,int ESZ,int NY,int NTOT,int ACT,int RES,int LNF,int STATS,int OUT,int HASB>
__global__ __launch_bounds__(256,2) void gemm_kernel(
    const void* __restrict__ Av, const void* __restrict__ Bv,
    const float* __restrict__ bias, const u16* __restrict__ res,
    void* __restrict__ out,
    const float2* __restrict__ RSin, const float* __restrict__ wsum,
    const float* __restrict__ cc, float2* __restrict__ RSout,
    float ascale)
{
    constexpr int NKT = (KEL*ESZ)/128;
    constexpr int KKS = (ESZ==1)?4:2;
    constexpr int PITCH = KEL*ESZ;
    __shared__ __align__(16) u16 lds[40960];
    const int tid = threadIdx.x;
    const int wv = tid>>6, l = tid&63, lr = l&15, lg = l>>4;
    const int wm = wv&1, wn = wv>>1;
    const int chunk = gridDim.x >> 3;
    const int orig = (blockIdx.x & 7)*chunk + (blockIdx.x >> 3);
    const int mt = orig / NY;
    const int nc = orig - mt*NY;
    const size_t row0 = (size_t)mt*128;
    const int n0 = nc*192;
    const char* A = (const char*)Av;
    const char* Bblk = (const char*)Bv + (size_t)n0*PITCH;

    stage_tile<128>(A, row0, 0, PITCH, lds, tid);
    stage_tile<192>(Bblk, 0, 0, PITCH, lds+16384, tid);
    __syncthreads();

    fx4 acc[4][6] = {};
    for (int kc=0; kc<NKT; ++kc){
        const int cur = kc & 1;
        u16* Ac = cur ? (u16*)lds+8192  : (u16*)lds;
        u16* Bc = cur ? (u16*)lds+28672 : (u16*)lds+16384;
        if (kc+1 < NKT){
            u16* An = cur ? (u16*)lds       : (u16*)lds+8192;
            u16* Bn = cur ? (u16*)lds+16384 : (u16*)lds+28672;
            stage_tile<128>(A, row0, kc+1, PITCH, An, tid);
            stage_tile<192>(Bblk, 0, kc+1, PITCH, Bn, tid);
        }
        #pragma unroll
        for (int kk=0; kk<KKS; ++kk){
            if constexpr (ESZ==2){
                bf8 af[4], bfr[6];
                #pragma unroll
                for (int r=0;r<4;r++) af[r]  = rd_frag16(Ac, wm*64 + r*16 + lr, kk*64 + lg*16);
                #pragma unroll
                for (int c=0;c<6;c++) bfr[c] = rd_frag16(Bc, wn*96 + c*16 + lr, kk*64 + lg*16);
                #pragma unroll
                for (int r=0;r<4;r++)
                    #pragma unroll
                    for (int c=0;c<6;c++)
                        acc[r][c] = __builtin_amdgcn_mfma_f32_16x16x32_bf16(af[r], bfr[c], acc[r][c], 0,0,0);
            } else {
                long af[4], bfr[6];
                #pragma unroll
                for (int r=0;r<4;r++) af[r]  = rd_frag8(Ac, wm*64 + r*16 + lr, kk*32 + lg*8);
                #pragma unroll
                for (int c=0;c<6;c++) bfr[c] = rd_frag8(Bc, wn*96 + c*16 + lr, kk*32 + lg*8);
                #pragma unroll
                for (int r=0;r<4;r++)
                    #pragma unroll
                    for (int c=0;c<6;c++)
                        acc[r][c] = __builtin_amdgcn_mfma_f32_16x16x32_fp8_fp8(af[r], bfr[c], acc[r][c], 0,0,0);
            }
        }
        __syncthreads();
    }

    // ---- epilogue ----
    float sA[4][4], sB[4][4];
    if constexpr (LNF){
        #pragma unroll
        for (int r=0;r<4;r++)
            #pragma unroll
            for (int q=0;q<4;q++){
                const float2 st = RSin[row0 + wm*64 + r*16 + lg*4 + q];
                sA[r][q] = st.y;
                sB[r][q] = -st.x*st.y;
            }
    }
    float ss[4][4], ss2[4][4];
    if constexpr (STATS){
        #pragma unroll
        for (int r=0;r<4;r++)
            #pragma unroll
            for (int q=0;q<4;q++){ ss[r][q]=0.f; ss2[r][q]=0.f; }
    }
    #pragma unroll
    for (int c=0;c<6;c++){
        const int col = n0 + wn*96 + c*16 + lr;
        float bv = 0.f, wsc = 0.f, ccc = 0.f;
        if constexpr (HASB) bv = bias[col];
        if constexpr (LNF){ wsc = wsum[col]; ccc = cc[col]; }
        #pragma unroll
        for (int r=0;r<4;r++){
            const size_t grow0 = row0 + wm*64 + r*16 + lg*4;
            float vq[4];
            #pragma unroll
            for (int q=0;q<4;q++){
                float v = acc[r][c][q];
                if constexpr (ESZ==1) v *= ascale;
                if constexpr (LNF) v = fmaf(v, sA[r][q], fmaf(sB[r][q], wsc, ccc));
                else v += bv;
                if constexpr (ACT) v = gelu_f(v);
                if constexpr (RES) v += b2f(res[(grow0+q)*NTOT + col]);
                if constexpr (STATS){ ss[r][q] += v; ss2[r][q] += v*v; }
                vq[q] = v;
            }
            if constexpr (OUT==1){
                u16* ob = (u16*)out + grow0*NTOT + col;
                ob[0] = f2bu(vq[0]);
                ob[NTOT] = f2bu(vq[1]);
                ob[2*NTOT] = f2bu(vq[2]);
                ob[3*NTOT] = f2bu(vq[3]);
            } else {
                u8* ob = (u8*)out + grow0*(size_t)NTOT + col;
#if __has_builtin(__builtin_amdgcn_cvt_pk_fp8_f32)
                const u32 p01 = (u32)__builtin_amdgcn_cvt_pk_fp8_f32(vq[0], vq[1], 0, false);
                const u32 p23 = (u32)__builtin_amdgcn_cvt_pk_fp8_f32(vq[2], vq[3], 0, false);
                ob[0] = (u8)p01;
                ob[NTOT] = (u8)(p01>>8);
                ob[2*NTOT] = (u8)p23;
                ob[3*NTOT] = (u8)(p23>>8);
#else
                ob[0] = f2f8(vq[0]);
                ob[NTOT] = f2f8(vq[1]);
                ob[2*NTOT] = f2f8(vq[2]);
                ob[3*NTOT] = f2f8(vq[3]);
#endif
            }
        }
    }
    if constexpr (STATS){
        float* redS = (float*)lds;     // [2][128][2]
        #pragma unroll
        for (int r=0;r<4;r++)
            #pragma unroll
            for (int q=0;q<4;q++){
                float s = ss[r][q], s2 = ss2[r][q];
                #pragma unroll
                for (int o=8;o;o>>=1){ s += __shfl_xor(s, o, 64); s2 += __shfl_xor(s2, o, 64); }
                if (lr == 0){
                    const int rowl = wm*64 + r*16 + lg*4 + q;
                    redS[(wn*128 + rowl)*2 + 0] = s;
                    redS[(wn*128 + rowl)*2 + 1] = s2;
                }
            }
        __syncthreads();
        for (int row = tid; row < 128; row += 256){
            const float S  = redS[row*2+0] + redS[(128+row)*2+0];
            const float S2 = redS[row*2+1] + redS[(128+row)*2+1];
            const float mean = S*(1.f/192.f);
            const float rstd = frsq(S2*(1.f/192.f) - mean*mean + 1e-5f);
            RSout[row0 + row] = make_float2(mean, rstd);
        }
    }
}

// ---- attention: 2 waves/block = 2 heads of one window ----
__global__ __launch_bounds__(128) void attn_kernel(const u16* __restrict__ qkv,
                                                   const float* __restrict__ LT,
                                                   u16* __restrict__ o)
{
    __shared__ u16 paS[2][50*64];
    __shared__ u16 vtS[2][32*64];
    const int w2 = threadIdx.x>>6;
    const int bid = blockIdx.x;              // 12288: widx*3 + hp
    const int widx = bid/3, hp = bid - widx*3;
    const int h = hp*2 + w2;
    u16* pa = paS[w2];
    u16* vt = vtS[w2];
    const int wi = widx & 63;
    const int nhi = wi>>3, nwi = wi&7;
    const int l = threadIdx.x & 63, lr = l&15, lg = l>>4;
    const u16* base = qkv + (size_t)widx*49*576;
    const int cls = ((nhi==7)?2:0) | ((nwi==7)?1:0);
    const float* Ths = LT + (size_t)(cls*6 + h)*4096 + l*64;

    bf8 qf[4], kf[4];
    #pragma unroll
    for (int t=0;t<4;t++){
        const int row = min(t*16 + lr, 48);
        qf[t] = *(const bf8*)(base + (size_t)row*576 + h*32 + lg*8);
        kf[t] = *(const bf8*)(base + (size_t)row*576 + 192 + h*32 + lg*8);
    }
    for (int e=l; e<480; e+=64){
        int d = e/15, j = 49 + (e - d*15);
        vt[d*64 + (j ^ (((d>>1)&7)<<3))] = 0;
    }
    for (int e=l; e<784; e+=64){
        int j = e>>4, dp = e&15;
        u32 val = *(const u32*)(base + (size_t)j*576 + 384 + h*32 + dp*2);
        const int d0 = dp*2, d1 = d0+1;
        vt[d0*64 + (j ^ ((dp&7)<<3))] = (u16)(val & 0xffffu);
        vt[d1*64 + (j ^ ((dp&7)<<3))] = (u16)(val >> 16);
    }

    fx4 acc[4][4] = {};
    #pragma unroll
    for (int ti=0;ti<4;ti++)
        #pragma unroll
        for (int tj=0;tj<4;tj++)
            acc[ti][tj] = __builtin_amdgcn_mfma_f32_16x16x32_bf16(qf[ti], kf[tj], acc[ti][tj], 0,0,0);

    #pragma unroll
    for (int ti=0;ti<4;ti++){
        #pragma unroll
        for (int reg=0;reg<4;reg++){
            const fx4 lt = *(const fx4*)(Ths + ti*16 + reg*4);
            #pragma unroll
            for (int tj=0;tj<4;tj++)
                acc[ti][tj][reg] = fmaf(acc[ti][tj][reg], SCALE2, lt[tj]);
        }
    }
    float sums[4][4];
    #pragma unroll
    for (int ti=0;ti<4;ti++){
        #pragma unroll
        for (int reg=0;reg<4;reg++){
            float mx = fmaxf(fmaxf(acc[ti][0][reg], acc[ti][1][reg]),
                             fmaxf(acc[ti][2][reg], acc[ti][3][reg]));
            #pragma unroll
            for (int o2=8;o2;o2>>=1) mx = fmaxf(mx, __shfl_xor(mx, o2, 64));
            float sum = 0.f;
            #pragma unroll
            for (int tj=0;tj<4;tj++){
                float p = __builtin_amdgcn_exp2f(acc[ti][tj][reg] - mx);
                acc[ti][tj][reg] = p;
                sum += p;
            }
            #pragma unroll
            for (int o2=8;o2;o2>>=1) sum += __shfl_xor(sum, o2, 64);
            sums[ti][reg] = sum;
        }
    }
    #pragma unroll
    for (int ti=0;ti<4;ti++)
        #pragma unroll
        for (int tj=0;tj<4;tj++)
            #pragma unroll
            for (int reg=0;reg<4;reg++){
                const int row = ti*16 + lg*4 + reg;
                if (row < 50)
                    pa[row*64 + ((tj*16+lr) ^ ((row&7)<<3))] = f2bu(acc[ti][tj][reg]);
            }
    __syncthreads();

    fx4 oacc[4][2] = {};
    #pragma unroll
    for (int kk=0;kk<2;kk++){
        bf8 bfr[2];
        #pragma unroll
        for (int cd=0;cd<2;cd++){
            const int rowb = cd*16 + lr;
            bfr[cd] = *(const bf8*)(vt + rowb*64 + ((kk*32 + lg*8) ^ (((rowb>>1)&7)<<3)));
        }
        #pragma unroll
        for (int ti=0;ti<4;ti++){
            const int rowa = min(ti*16 + lr, 49);
            bf8 afr = *(const bf8*)(pa + rowa*64 + ((kk*32 + lg*8) ^ ((rowa&7)<<3)));
            #pragma unroll
            for (int cd=0;cd<2;cd++)
                oacc[ti][cd] = __builtin_amdgcn_mfma_f32_16x16x32_bf16(afr, bfr[cd], oacc[ti][cd], 0,0,0);
        }
    }
    u16* ob = o + (size_t)widx*49*192 + h*32;
    #pragma unroll
    for (int ti=0;ti<4;ti++){
        float rsv[4];
        #pragma unroll
        for (int q=0;q<4;q++) rsv[q] = frcp(sums[ti][q]);
        #pragma unroll
        for (int cd=0;cd<2;cd++)
            #pragma unroll
            for (int q=0;q<4;q++){
                const int i = ti*16 + lg*4 + q;
                if (i < 49) ob[(size_t)i*192 + cd*16 + lr] = f2bu(oacc[ti][cd][q]*rsv[q]);
            }
    }
}

extern "C" void kernel_launch(void* const* d_in, const int* in_sizes, int n_in,
                              void* d_out, int out_size, void* d_ws, size_t ws_size,
                              hipStream_t stream)
{
    const float* x      = (const float*)d_in[0];
    const float* ln1_g  = (const float*)d_in[1];
    const float* ln1_b  = (const float*)d_in[2];
    const float* qkv_w  = (const float*)d_in[3];
    const float* out_w  = (const float*)d_in[4];
    const float* out_b  = (const float*)d_in[5];
    const float* ln2_g  = (const float*)d_in[6];
    const float* ln2_b  = (const float*)d_in[7];
    const float* mlp_w1 = (const float*)d_in[8];
    const float* mlp_b1 = (const float*)d_in[9];
    const float* mlp_w2 = (const float*)d_in[10];
    const float* mlp_b2 = (const float*)d_in[11];
    const float* rel_t  = (const float*)d_in[12];

    char* ws = (char*)d_ws;
    u16*    Ybuf  = (u16*)ws;                    // O (attn out) / xw3 bf16 [T,192]
    float*  LTab  = (float*)(ws + 77070336);
    float2* RS1   = (float2*)(ws + 77600000);
    float2* RS2   = (float2*)(ws + 79300000);
    u16*    WqP   = (u16*)(ws + 81000000);
    float*  wsq   = (float*)(ws + 81300000);
    float*  ccq   = (float*)(ws + 81310000);
    u16*    W1P   = (u16*)(ws + 81400000);
    float*  ws1   = (float*)(ws + 81700000);
    float*  cc1   = (float*)(ws + 81710000);
    u16*    XWbuf = (u16*)(ws + 154140672);
    u16*    QKVH  = (u16*)(ws + 231211008);
    u8*     Hbuf  = (u8*)(ws + 231211008);
    u16*    Wo    = (u16*)(ws + 539492352);
    u8*     W2f8  = (u8*)(ws + 539492352 + 73728);

    f2b2_kernel<<<576,256,0,stream>>>(out_w, mlp_w2, Wo, W2f8);
    wprep_kernel<<<336,256,0,stream>>>(qkv_w, ln1_g, ln1_b, mlp_w1, ln2_g, ln2_b, mlp_b1,
                                       WqP, wsq, ccq, W1P, ws1, cc1);
    ltab_kernel<<<24,256,0,stream>>>(rel_t, LTab);

    // partition + LN1 stats
    partition_ln_kernel<<<3584,256,0,stream>>>(x, XWbuf, RS1);
    // qkv = LN1(xw) @ Wq^T (folded) : [T,576] bf16
    gemm_kernel<192,2,3,576,0,0,1,0,1,0><<<4704,256,0,stream>>>(
        XWbuf, WqP, nullptr, nullptr, QKVH, RS1, wsq, ccq, nullptr, 1.f);
    attn_kernel<<<12288,128,0,stream>>>(QKVH, LTab, Ybuf);
    // xw2 = xw + O @ Wo^T + b (bf16, in-place); LN2 stats -> RS2
    gemm_kernel<192,2,1,192,0,1,0,1,1,1><<<1568,256,0,stream>>>(
        Ybuf, Wo, out_b, XWbuf, XWbuf, nullptr, nullptr, nullptr, RS2, 1.f);
    // h = gelu(LN2(xw2) @ W1^T + b1) (folded) : [T,768] fp8
    gemm_kernel<192,2,4,768,1,0,1,0,2,0><<<6272,256,0,stream>>>(
        XWbuf, W1P, nullptr, nullptr, Hbuf, RS2, ws1, cc1, nullptr, 1.f);
    // xw3 = xw2 + (h @ W2f8^T)/16 + b2 : bf16 -> Ybuf
    gemm_kernel<768,1,1,192,0,1,0,0,1,1><<<1568,256,0,stream>>>(
        Hbuf, W2f8, mlp_b2, XWbuf, Ybuf, nullptr, nullptr, nullptr, nullptr, 0.0625f);
    reverse_kernel<<<3584,256,0,stream>>>(Ybuf, (float*)d_out);
}

// Round 20
// 679.503 us; speedup vs baseline: 1.1592x; 1.0013x over previous
//
#include <hip/hip_runtime.h>
#include <hip/hip_bf16.h>
#include <hip/hip_fp8.h>

typedef unsigned short u16;
typedef unsigned int u32;
typedef unsigned char u8;
typedef __attribute__((ext_vector_type(4))) float fx4;
typedef __attribute__((ext_vector_type(8))) __bf16 bf8;

#define NEGV -1e9f
#define LOG2E 1.4426950408889634f
#define SCALE2 (0.17677669529663687f*1.4426950408889634f)

static __device__ __forceinline__ u16 f2bu(float f){
    __hip_bfloat16 h = __float2bfloat16(f);
    return *reinterpret_cast<u16*>(&h);
}
static __device__ __forceinline__ float b2f(u16 u){
    __hip_bfloat16 h;
    *reinterpret_cast<u16*>(&h) = u;
    return __bfloat162float(h);
}
static __device__ __forceinline__ u8 f2f8(float v){
    __hip_fp8_e4m3 t(v);
    return *reinterpret_cast<u8*>(&t);
}
static __device__ __forceinline__ float frcp(float x){
#if __has_builtin(__builtin_amdgcn_rcpf)
    return __builtin_amdgcn_rcpf(x);
#else
    return 1.f/x;
#endif
}
static __device__ __forceinline__ float frsq(float x){
#if __has_builtin(__builtin_amdgcn_rsqf)
    return __builtin_amdgcn_rsqf(x);
#else
    return rsqrtf(x);
#endif
}
// GELU via v*sigmoid(1.702v) — error below the fp8 h-buffer quantization noise.
static __device__ __forceinline__ float gelu_f(float v){
    return v * frcp(1.f + __builtin_amdgcn_exp2f(-2.4554418f*v));
}

// ---- K0a: Wo -> bf16 ; W2*16 -> fp8 e4m3 ----
__global__ __launch_bounds__(256) void f2b2_kernel(
        const float* __restrict__ s1, const float* __restrict__ s3,
        u16* __restrict__ d1, u8* __restrict__ d3){
    int i = blockIdx.x*256 + threadIdx.x;
    if (i < 36864)  d1[i] = f2bu(s1[i]);
    if (i < 147456) d3[i] = f2f8(s3[i]*16.f);
}

// ---- K0b: LN-folded weights ----
__global__ __launch_bounds__(256) void wprep_kernel(
        const float* __restrict__ qkv_w, const float* __restrict__ g1, const float* __restrict__ b1,
        const float* __restrict__ w1,    const float* __restrict__ g2, const float* __restrict__ b2,
        const float* __restrict__ mb1,
        u16* __restrict__ WqP, float* __restrict__ wsq, float* __restrict__ ccq,
        u16* __restrict__ W1P, float* __restrict__ ws1, float* __restrict__ cc1){
    const int row = blockIdx.x*4 + (threadIdx.x>>6);
    const int l = threadIdx.x & 63;
    const int isq = row < 576;
    const int n = isq ? row : row - 576;
    if (row >= 1344) return;
    const float* src = (isq ? qkv_w : w1) + (size_t)n*192;
    const float* g = isq ? g1 : g2;
    const float* b = isq ? b1 : b2;
    u16* dst = (isq ? WqP : W1P) + (size_t)n*192;
    float sw = 0.f, sc = 0.f;
    #pragma unroll
    for (int t=0;t<3;t++){
        const int k = l + t*64;
        const float wv = src[k];
        const float wp = wv*g[k];
        dst[k] = f2bu(wp);
        sw += wp; sc += b[k]*wv;
    }
    #pragma unroll
    for (int o=32;o;o>>=1){ sw += __shfl_xor(sw,o,64); sc += __shfl_xor(sc,o,64); }
    if (!l){
        if (isq){ wsq[n]=sw; ccq[n]=sc; }
        else    { ws1[n]=sw; cc1[n]=sc + mb1[n]; }
    }
}

// ---- fused logit table, PER-LANE FRAGMENT LAYOUT:
// LT[cls*6+h][lane][ti][reg][tj] = (rel_bias + shift_mask)*LOG2E, NEG pads.
__global__ __launch_bounds__(256) void ltab_kernel(const float* __restrict__ rel_table,
                                                   float* __restrict__ LT){
    const int blk = blockIdx.x;           // cls*6 + h
    const int cls = blk/6, h = blk - cls*6;
    float* T = LT + blk*4096;
    for (int e = threadIdx.x; e < 4096; e += 256){
        const int lane = e>>6, rem = e&63;
        const int ti = rem>>4, reg = (rem>>2)&3, tj = rem&3;
        const int lg = lane>>4, lr = lane&15;
        const int i = ti*16 + lg*4 + reg;
        const int j = tj*16 + lr;
        float v = NEGV;
        if (i < 49 && j < 49){
            const int id = i/7, im = i-id*7, jd = j/7, jm = j-jd*7;
            const int ridx = (id-jd+6)*13 + (im-jm+6);
            const float bias = rel_table[ridx*6 + h];
            const int ri = (cls&2) ? (id<4?1:2) : 0;
            const int rj = (cls&2) ? (jd<4?1:2) : 0;
            const int ci = (cls&1) ? (im<4?1:2) : 0;
            const int cj = (cls&1) ? (jm<4?1:2) : 0;
            v = bias + ((ri==rj && ci==cj) ? 0.f : NEGV);
        }
        T[e] = v * LOG2E;
    }
}

// ---- K1: roll(-3,-3) + window partition; LN1 stats only ----
__global__ __launch_bounds__(256) void partition_ln_kernel(
        const float* __restrict__ x, u16* __restrict__ xw, float2* __restrict__ RS1){
    __shared__ float lds[192*57];
    const int bi = blockIdx.x;
    const int b = bi/56, i = bi%56;
    const int si = (i+3)%56;
    const float* src = x + (size_t)b*602112 + (size_t)si*56;
    for (int e = threadIdx.x; e < 10752; e += 256){
        int c = e/56, j = e%56;
        lds[c*57 + j] = src[(size_t)c*3136 + j];
    }
    __syncthreads();
    const int wrow_base = (b*8 + i/7)*8;
    const int prow = (i%7)*7;
    for (int e = threadIdx.x; e < 10752; e += 256){
        int j = e/192, c = e%192;
        int t = (wrow_base + j/7)*49 + prow + (j%7);
        xw[(size_t)t*192 + c] = f2bu(lds[c*57 + (j+3)%56]);
    }
    const int wv = threadIdx.x>>6, l = threadIdx.x&63;
    for (int j = wv; j < 56; j += 4){
        const int jj = (j+3)%56;
        float v0 = lds[l*57 + jj], v1 = lds[(l+64)*57 + jj], v2 = lds[(l+128)*57 + jj];
        float s = v0+v1+v2;
        #pragma unroll
        for (int o=32;o;o>>=1) s += __shfl_xor(s, o, 64);
        const float mean = s*(1.f/192.f);
        float d0 = v0-mean, d1 = v1-mean, d2 = v2-mean;
        float qv = d0*d0 + d1*d1 + d2*d2;
        #pragma unroll
        for (int o=32;o;o>>=1) qv += __shfl_xor(qv, o, 64);
        const float rstd = frsq(qv*(1.f/192.f) + 1e-5f);
        if (l == 0){
            const int t = (wrow_base + j/7)*49 + prow + (j%7);
            RS1[t] = make_float2(mean, rstd);
        }
    }
}

// ---- K9: window reverse + roll(+3,+3): bf16 -> f32 ----
__global__ __launch_bounds__(256) void reverse_kernel(const u16* __restrict__ xw, float* __restrict__ out){
    __shared__ float lds[192*57];
    const int bi = blockIdx.x;
    const int b = bi/56, h = bi%56;
    const int i = (h+53)%56;
    const int wrow_base = (b*8 + i/7)*8;
    const int prow = (i%7)*7;
    for (int e = threadIdx.x; e < 10752; e += 256){
        int j = e/192, c = e%192;
        int t = (wrow_base + j/7)*49 + prow + (j%7);
        lds[c*57 + j] = b2f(xw[(size_t)t*192 + c]);
    }
    __syncthreads();
    float* dst = out + (size_t)b*602112 + (size_t)h*56;
    for (int e = threadIdx.x; e < 10752; e += 256){
        int c = e/56, w = e%56;
        dst[(size_t)c*3136 + w] = lds[c*57 + (w+53)%56];
    }
}

// ---- staging: global -> LDS, 128-byte-wide tile rows, XOR-pre-swizzled source ----
template<int ROWS>
static __device__ __forceinline__ void stage_tile(const char* __restrict__ g, size_t row0,
                                                  int kc, int pitch, u16* ldsbase, int tid){
    const int w = tid>>6, lane = tid&63;
    const int sub = lane>>3;
    const int b16 = (lane&7) ^ sub;
    #pragma unroll
    for (int i=0; i<ROWS/32; ++i){
        const int row = i*32 + w*8 + sub;
        const char* src = g + (row0+row)*(size_t)pitch + (size_t)kc*128 + b16*16;
        u16* dst = ldsbase + i*2048 + w*512;
#if __has_builtin(__builtin_amdgcn_global_load_lds)
        __builtin_amdgcn_global_load_lds(
            (const __attribute__((address_space(1))) u32*)src,
            (__attribute__((address_space(3))) u32*)dst, 16, 0, 0);
#else
        *(uint4*)(dst + lane*8) = *(const uint4*)src;
#endif
    }
}

static __device__ __forceinline__ bf8 rd_frag16(const u16* lds, int row, int boff){
    const char* p = (const char*)lds + row*128 + (boff ^ ((row&7)<<4));
    return *(const bf8*)p;
}
static __device__ __forceinline__ long rd_frag8(const u16* lds, int row, int boff){
    const char* p = (const char*)lds + row*128 + (boff ^ ((row&7)<<4));
    return *(const long*)p;
}

// ---- pipelined GEMM: BM=128, BN=192, 128B K-chunks, double-buffered ----
template<int KEL,int ESZ,int NY,int NTOT,int ACT,int RES,int LNF,int STATS,int OUT,int HASB>
__global__ __launch_bounds__(256,2) void gemm_kernel(
    const void* __restrict__ Av, const void* __restrict__ Bv,
    const float* __restrict__ bias, const u16* __restrict__ res,
    void* __restrict__ out,
    const float2* __restrict__ RSin, const float* __restrict__ wsum,
    const float* __restrict__ cc, float2* __restrict__ RSout,
    float ascale)
{
    constexpr int NKT = (KEL*ESZ)/128;
    constexpr int KKS = (ESZ==1)?4:2;
    constexpr int PITCH = KEL*ESZ;
    __shared__ __align__(16) u16 lds[40960];
    const int tid = threadIdx.x;
    const int wv = tid>>6, l = tid&63, lr = l&15, lg = l>>4;
    const int wm = wv&1, wn = wv>>1;
    const int chunk = gridDim.x >> 3;
    const int orig = (blockIdx.x & 7)*chunk + (blockIdx.x >> 3);
    const int mt = orig / NY;
    const int nc = orig - mt*NY;
    const size_t row0 = (size_t)mt*128;
    const int n0 = nc*192;
    const char* A = (const char*)Av;
    const char* Bblk = (const char*)Bv + (size_t)n0*PITCH;

    stage_tile<128>(A, row0, 0, PITCH, lds, tid);
    stage_tile<192>(Bblk, 0, 0, PITCH, lds+16384, tid);
    __syncthreads();

    fx4 acc[4][6] = {};
    for (int kc=0; kc<NKT; ++kc){
        const int cur = kc & 1;
        u16* Ac = cur ? (u16*)lds+8192  : (u16*)lds;
        u16* Bc = cur ? (u16*)lds+28672 : (u16*)lds+16384;
        if (kc+1 < NKT){
            u16* An = cur ? (u16*)lds       : (u16*)lds+8192;
            u16* Bn = cur ? (u16*)lds+16384 : (u16*)lds+28672;
            stage_tile<128>(A, row0, kc+1, PITCH, An, tid);
            stage_tile<192>(Bblk, 0, kc+1, PITCH, Bn, tid);
        }
        #pragma unroll
        for (int kk=0; kk<KKS; ++kk){
            if constexpr (ESZ==2){
                bf8 af[4], bfr[6];
                #pragma unroll
                for (int r=0;r<4;r++) af[r]  = rd_frag16(Ac, wm*64 + r*16 + lr, kk*64 + lg*16);
                #pragma unroll
                for (int c=0;c<6;c++) bfr[c] = rd_frag16(Bc, wn*96 + c*16 + lr, kk*64 + lg*16);
                #pragma unroll
                for (int r=0;r<4;r++)
                    #pragma unroll
                    for (int c=0;c<6;c++)
                        acc[r][c] = __builtin_amdgcn_mfma_f32_16x16x32_bf16(af[r], bfr[c], acc[r][c], 0,0,0);
            } else {
                long af[4], bfr[6];
                #pragma unroll
                for (int r=0;r<4;r++) af[r]  = rd_frag8(Ac, wm*64 + r*16 + lr, kk*32 + lg*8);
                #pragma unroll
                for (int c=0;c<6;c++) bfr[c] = rd_frag8(Bc, wn*96 + c*16 + lr, kk*32 + lg*8);
                #pragma unroll
                for (int r=0;r<4;r++)
                    #pragma unroll
                    for (int c=0;c<6;c++)
                        acc[r][c] = __builtin_amdgcn_mfma_f32_16x16x32_fp8_fp8(af[r], bfr[c], acc[r][c], 0,0,0);
            }
        }
        __syncthreads();
    }

    // ---- epilogue ----
    float sA[4][4], sB[4][4];
    if constexpr (LNF){
        #pragma unroll
        for (int r=0;r<4;r++)
            #pragma unroll
            for (int q=0;q<4;q++){
                const float2 st = RSin[row0 + wm*64 + r*16 + lg*4 + q];
                sA[r][q] = st.y;
                sB[r][q] = -st.x*st.y;
            }
    }
    float ss[4][4], ss2[4][4];
    if constexpr (STATS){
        #pragma unroll
        for (int r=0;r<4;r++)
            #pragma unroll
            for (int q=0;q<4;q++){ ss[r][q]=0.f; ss2[r][q]=0.f; }
    }
    #pragma unroll
    for (int c=0;c<6;c++){
        const int col = n0 + wn*96 + c*16 + lr;
        float bv = 0.f, wsc = 0.f, ccc = 0.f;
        if constexpr (HASB) bv = bias[col];
        if constexpr (LNF){ wsc = wsum[col]; ccc = cc[col]; }
        #pragma unroll
        for (int r=0;r<4;r++){
            const size_t grow0 = row0 + wm*64 + r*16 + lg*4;
            float vq[4];
            #pragma unroll
            for (int q=0;q<4;q++){
                float v = acc[r][c][q];
                if constexpr (ESZ==1) v *= ascale;
                if constexpr (LNF) v = fmaf(v, sA[r][q], fmaf(sB[r][q], wsc, ccc));
                else v += bv;
                if constexpr (ACT) v = gelu_f(v);
                if constexpr (RES) v += b2f(res[(grow0+q)*NTOT + col]);
                if constexpr (STATS){ ss[r][q] += v; ss2[r][q] += v*v; }
                vq[q] = v;
            }
            if constexpr (OUT==1){
                u16* ob = (u16*)out + grow0*NTOT + col;
                ob[0] = f2bu(vq[0]);
                ob[NTOT] = f2bu(vq[1]);
                ob[2*NTOT] = f2bu(vq[2]);
                ob[3*NTOT] = f2bu(vq[3]);
            } else {
                u8* ob = (u8*)out + grow0*(size_t)NTOT + col;
#if __has_builtin(__builtin_amdgcn_cvt_pk_fp8_f32)
                const u32 p01 = (u32)__builtin_amdgcn_cvt_pk_fp8_f32(vq[0], vq[1], 0, false);
                const u32 p23 = (u32)__builtin_amdgcn_cvt_pk_fp8_f32(vq[2], vq[3], 0, false);
                ob[0] = (u8)p01;
                ob[NTOT] = (u8)(p01>>8);
                ob[2*NTOT] = (u8)p23;
                ob[3*NTOT] = (u8)(p23>>8);
#else
                ob[0] = f2f8(vq[0]);
                ob[NTOT] = f2f8(vq[1]);
                ob[2*NTOT] = f2f8(vq[2]);
                ob[3*NTOT] = f2f8(vq[3]);
#endif
            }
        }
    }
    if constexpr (STATS){
        float* redS = (float*)lds;     // [2][128][2]
        #pragma unroll
        for (int r=0;r<4;r++)
            #pragma unroll
            for (int q=0;q<4;q++){
                float s = ss[r][q], s2 = ss2[r][q];
                #pragma unroll
                for (int o=8;o;o>>=1){ s += __shfl_xor(s, o, 64); s2 += __shfl_xor(s2, o, 64); }
                if (lr == 0){
                    const int rowl = wm*64 + r*16 + lg*4 + q;
                    redS[(wn*128 + rowl)*2 + 0] = s;
                    redS[(wn*128 + rowl)*2 + 1] = s2;
                }
            }
        __syncthreads();
        for (int row = tid; row < 128; row += 256){
            const float S  = redS[row*2+0] + redS[(128+row)*2+0];
            const float S2 = redS[row*2+1] + redS[(128+row)*2+1];
            const float mean = S*(1.f/192.f);
            const float rstd = frsq(S2*(1.f/192.f) - mean*mean + 1e-5f);
            RSout[row0 + row] = make_float2(mean, rstd);
        }
    }
}

// ---- attention: 2 waves/block = 2 heads of one window; NO inter-wave barrier
// (pa/vt are wave-private; same-wave LDS write->read is ordered by the
// compiler-inserted lgkmcnt waits, so the block barrier was pure coupling) ----
__global__ __launch_bounds__(128) void attn_kernel(const u16* __restrict__ qkv,
                                                   const float* __restrict__ LT,
                                                   u16* __restrict__ o)
{
    __shared__ u16 paS[2][50*64];
    __shared__ u16 vtS[2][32*64];
    const int w2 = threadIdx.x>>6;
    const int bid = blockIdx.x;              // 12288: widx*3 + hp
    const int widx = bid/3, hp = bid - widx*3;
    const int h = hp*2 + w2;
    u16* pa = paS[w2];
    u16* vt = vtS[w2];
    const int wi = widx & 63;
    const int nhi = wi>>3, nwi = wi&7;
    const int l = threadIdx.x & 63, lr = l&15, lg = l>>4;
    const u16* base = qkv + (size_t)widx*49*576;
    const int cls = ((nhi==7)?2:0) | ((nwi==7)?1:0);
    const float* Ths = LT + (size_t)(cls*6 + h)*4096 + l*64;

    bf8 qf[4], kf[4];
    #pragma unroll
    for (int t=0;t<4;t++){
        const int row = min(t*16 + lr, 48);
        qf[t] = *(const bf8*)(base + (size_t)row*576 + h*32 + lg*8);
        kf[t] = *(const bf8*)(base + (size_t)row*576 + 192 + h*32 + lg*8);
    }
    for (int e=l; e<480; e+=64){
        int d = e/15, j = 49 + (e - d*15);
        vt[d*64 + (j ^ (((d>>1)&7)<<3))] = 0;
    }
    for (int e=l; e<784; e+=64){
        int j = e>>4, dp = e&15;
        u32 val = *(const u32*)(base + (size_t)j*576 + 384 + h*32 + dp*2);
        const int d0 = dp*2, d1 = d0+1;
        vt[d0*64 + (j ^ ((dp&7)<<3))] = (u16)(val & 0xffffu);
        vt[d1*64 + (j ^ ((dp&7)<<3))] = (u16)(val >> 16);
    }

    fx4 acc[4][4] = {};
    #pragma unroll
    for (int ti=0;ti<4;ti++)
        #pragma unroll
        for (int tj=0;tj<4;tj++)
            acc[ti][tj] = __builtin_amdgcn_mfma_f32_16x16x32_bf16(qf[ti], kf[tj], acc[ti][tj], 0,0,0);

    #pragma unroll
    for (int ti=0;ti<4;ti++){
        #pragma unroll
        for (int reg=0;reg<4;reg++){
            const fx4 lt = *(const fx4*)(Ths + ti*16 + reg*4);
            #pragma unroll
            for (int tj=0;tj<4;tj++)
                acc[ti][tj][reg] = fmaf(acc[ti][tj][reg], SCALE2, lt[tj]);
        }
    }
    float sums[4][4];
    #pragma unroll
    for (int ti=0;ti<4;ti++){
        #pragma unroll
        for (int reg=0;reg<4;reg++){
            float mx = fmaxf(fmaxf(acc[ti][0][reg], acc[ti][1][reg]),
                             fmaxf(acc[ti][2][reg], acc[ti][3][reg]));
            #pragma unroll
            for (int o2=8;o2;o2>>=1) mx = fmaxf(mx, __shfl_xor(mx, o2, 64));
            float sum = 0.f;
            #pragma unroll
            for (int tj=0;tj<4;tj++){
                float p = __builtin_amdgcn_exp2f(acc[ti][tj][reg] - mx);
                acc[ti][tj][reg] = p;
                sum += p;
            }
            #pragma unroll
            for (int o2=8;o2;o2>>=1) sum += __shfl_xor(sum, o2, 64);
            sums[ti][reg] = sum;
        }
    }
    #pragma unroll
    for (int ti=0;ti<4;ti++)
        #pragma unroll
        for (int tj=0;tj<4;tj++)
            #pragma unroll
            for (int reg=0;reg<4;reg++){
                const int row = ti*16 + lg*4 + reg;
                if (row < 50)
                    pa[row*64 + ((tj*16+lr) ^ ((row&7)<<3))] = f2bu(acc[ti][tj][reg]);
            }
    // no __syncthreads(): pa/vt are wave-private; lgkmcnt ordering suffices.

    fx4 oacc[4][2] = {};
    #pragma unroll
    for (int kk=0;kk<2;kk++){
        bf8 bfr[2];
        #pragma unroll
        for (int cd=0;cd<2;cd++){
            const int rowb = cd*16 + lr;
            bfr[cd] = *(const bf8*)(vt + rowb*64 + ((kk*32 + lg*8) ^ (((rowb>>1)&7)<<3)));
        }
        #pragma unroll
        for (int ti=0;ti<4;ti++){
            const int rowa = min(ti*16 + lr, 49);
            bf8 afr = *(const bf8*)(pa + rowa*64 + ((kk*32 + lg*8) ^ ((rowa&7)<<3)));
            #pragma unroll
            for (int cd=0;cd<2;cd++)
                oacc[ti][cd] = __builtin_amdgcn_mfma_f32_16x16x32_bf16(afr, bfr[cd], oacc[ti][cd], 0,0,0);
        }
    }
    u16* ob = o + (size_t)widx*49*192 + h*32;
    #pragma unroll
    for (int ti=0;ti<4;ti++){
        float rsv[4];
        #pragma unroll
        for (int q=0;q<4;q++) rsv[q] = frcp(sums[ti][q]);
        #pragma unroll
        for (int cd=0;cd<2;cd++)
            #pragma unroll
            for (int q=0;q<4;q++){
                const int i = ti*16 + lg*4 + q;
                if (i < 49) ob[(size_t)i*192 + cd*16 + lr] = f2bu(oacc[ti][cd][q]*rsv[q]);
            }
    }
}

extern "C" void kernel_launch(void* const* d_in, const int* in_sizes, int n_in,
                              void* d_out, int out_size, void* d_ws, size_t ws_size,
                              hipStream_t stream)
{
    const float* x      = (const float*)d_in[0];
    const float* ln1_g  = (const float*)d_in[1];
    const float* ln1_b  = (const float*)d_in[2];
    const float* qkv_w  = (const float*)d_in[3];
    const float* out_w  = (const float*)d_in[4];
    const float* out_b  = (const float*)d_in[5];
    const float* ln2_g  = (const float*)d_in[6];
    const float* ln2_b  = (const float*)d_in[7];
    const float* mlp_w1 = (const float*)d_in[8];
    const float* mlp_b1 = (const float*)d_in[9];
    const float* mlp_w2 = (const float*)d_in[10];
    const float* mlp_b2 = (const float*)d_in[11];
    const float* rel_t  = (const float*)d_in[12];

    char* ws = (char*)d_ws;
    u16*    Ybuf  = (u16*)ws;                    // O (attn out) / xw3 bf16 [T,192]
    float*  LTab  = (float*)(ws + 77070336);
    float2* RS1   = (float2*)(ws + 77600000);
    float2* RS2   = (float2*)(ws + 79300000);
    u16*    WqP   = (u16*)(ws + 81000000);
    float*  wsq   = (float*)(ws + 81300000);
    float*  ccq   = (float*)(ws + 81310000);
    u16*    W1P   = (u16*)(ws + 81400000);
    float*  ws1   = (float*)(ws + 81700000);
    float*  cc1   = (float*)(ws + 81710000);
    u16*    XWbuf = (u16*)(ws + 154140672);
    u16*    QKVH  = (u16*)(ws + 231211008);
    u8*     Hbuf  = (u8*)(ws + 231211008);
    u16*    Wo    = (u16*)(ws + 539492352);
    u8*     W2f8  = (u8*)(ws + 539492352 + 73728);

    f2b2_kernel<<<576,256,0,stream>>>(out_w, mlp_w2, Wo, W2f8);
    wprep_kernel<<<336,256,0,stream>>>(qkv_w, ln1_g, ln1_b, mlp_w1, ln2_g, ln2_b, mlp_b1,
                                       WqP, wsq, ccq, W1P, ws1, cc1);
    ltab_kernel<<<24,256,0,stream>>>(rel_t, LTab);

    // partition + LN1 stats
    partition_ln_kernel<<<3584,256,0,stream>>>(x, XWbuf, RS1);
    // qkv = LN1(xw) @ Wq^T (folded) : [T,576] bf16
    gemm_kernel<192,2,3,576,0,0,1,0,1,0><<<4704,256,0,stream>>>(
        XWbuf, WqP, nullptr, nullptr, QKVH, RS1, wsq, ccq, nullptr, 1.f);
    attn_kernel<<<12288,128,0,stream>>>(QKVH, LTab, Ybuf);
    // xw2 = xw + O @ Wo^T + b (bf16, in-place); LN2 stats -> RS2
    gemm_kernel<192,2,1,192,0,1,0,1,1,1><<<1568,256,0,stream>>>(
        Ybuf, Wo, out_b, XWbuf, XWbuf, nullptr, nullptr, nullptr, RS2, 1.f);
    // h = gelu(LN2(xw2) @ W1^T + b1) (folded) : [T,768] fp8
    gemm_kernel<192,2,4,768,1,0,1,0,2,0><<<6272,256,0,stream>>>(
        XWbuf, W1P, nullptr, nullptr, Hbuf, RS2, ws1, cc1, nullptr, 1.f);
    // xw3 = xw2 + (h @ W2f8^T)/16 + b2 : bf16 -> Ybuf
    gemm_kernel<768,1,1,192,0,1,0,0,1,1><<<1568,256,0,stream>>>(
        Hbuf, W2f8, mlp_b2, XWbuf, Ybuf, nullptr, nullptr, nullptr, nullptr, 0.0625f);
    reverse_kernel<<<3584,256,0,stream>>>(Ybuf, (float*)d_out);
}